// Round 3
// baseline (17487.024 us; speedup 1.0000x reference)
//
#include <hip/hip_runtime.h>
#include <cstddef>

// DifferentiableRollout: x_{t+1} = x + DT * ( tanh([x,u]@W1 + b1) @ W2 + b2 )
// B=1024, T=200, SD=64, CD=32, H=512.  fp32 only (chaos amplifies bf16 noise
// ~1e4x past threshold -- measured R0: fp32 reorder noise alone -> absmax 0.25).
//
// R1 design (R2 = identical resubmit; R2's bench died in a Trio-nursery infra
// exception before producing a verdict -- kernel audited hang-free: uniform
// barriers, constant-indexed register arrays, ~180 VGPR < 256 cap, 17.5 KB LDS).
//  - 256 blocks x 512 threads, 4 rows/block, persistent across all 200 steps.
//  - Thread tid owns W1 column tid (96 VGPRs) for GEMM1: x broadcast from LDS
//    (wave-uniform float4 reads = bank-conflict-free broadcast), 4 rows ->
//    4 independent FMA chains on register weights.
//  - Wave jc (=tid>>6) owns W2 rows [jc*64, jc*64+64); thread (jc, s) holds
//    W2[j][s] for that chunk (64 VGPRs).  GEMM2 = per-wave rank-64 partials
//    with h broadcast from LDS, then 8-chunk reduction through LDS.
//  - Controls prefetched one step ahead (global load overlaps GEMM1).
//  - 3 barriers/step: h visible | partials visible | state+ctrl visible.

constexpr int B_  = 1024;
constexpr int T_  = 200;
constexpr int SD_ = 64;
constexpr int CD_ = 32;
constexpr int H_  = 512;
constexpr int KD_ = SD_ + CD_;   // 96
constexpr float DT_ = 0.1f;
constexpr int ROWS_ = 4;
constexpr int THREADS_ = 512;

__global__ __launch_bounds__(THREADS_, 2) void rollout_regw_kernel(
    const float* __restrict__ x0,     // [B, SD]
    const float* __restrict__ ctrl,   // [B, T, CD]
    const float* __restrict__ W1,     // [KD, H]
    const float* __restrict__ b1,     // [H]
    const float* __restrict__ W2,     // [H, SD]
    const float* __restrict__ b2,     // [SD]
    float* __restrict__ out)          // [B, T+1, SD]
{
    __shared__ float xcT[KD_][ROWS_];       // state+control, transposed (16B rows)
    __shared__ float hbuf[ROWS_][H_];       // activations
    __shared__ float part[ROWS_][SD_][8];   // GEMM2 partials [r][s][jc]

    const int tid = threadIdx.x;
    const int r0  = blockIdx.x * ROWS_;

    // ---- hoist weights into registers (once per 200 steps) ----
    float w1[KD_];
    #pragma unroll
    for (int k = 0; k < KD_; ++k)
        w1[k] = W1[(size_t)k * H_ + tid];          // coalesced: lanes j=tid

    const int jc = tid >> 6;                        // wave id 0..7 = W2 chunk
    const int sl = tid & 63;                        // lane 0..63 = output col s
    float w2[64];
    #pragma unroll
    for (int j = 0; j < 64; ++j)
        w2[j] = W2[(size_t)(jc * 64 + j) * SD_ + sl];  // coalesced per lane

    const float bj = b1[tid];

    // final-update mapping (tid < 256): (rf, sf)
    const int rf = (tid >> 6) & 3;
    const int sf = tid & 63;
    const float bs = b2[sf];

    // ctrl loader mapping: tid in [256, 384)
    const int  lt = tid - 256;
    const bool loader = (lt >= 0) && (lt < ROWS_ * CD_);
    const int  lr = (lt >> 5) & 3;
    const int  lc = lt & 31;
    const size_t ctrl_base = (size_t)(r0 + lr) * T_ * CD_ + lc;

    // ---- init: x0 into xcT + states[:,0,:], ctrl[0] into xcT ----
    if (tid < ROWS_ * SD_) {
        const float v = x0[(size_t)(r0 + rf) * SD_ + sf];
        xcT[sf][rf] = v;
        out[(size_t)(r0 + rf) * (T_ + 1) * SD_ + sf] = v;
    }
    if (loader) xcT[SD_ + lc][lr] = ctrl[ctrl_base];
    __syncthreads();

    for (int t = 0; t < T_; ++t) {
        // ---- prefetch next step's controls (consumed after barrier1) ----
        float cpre = 0.f;
        if (loader && (t + 1 < T_))
            cpre = ctrl[ctrl_base + (size_t)(t + 1) * CD_];

        // ---- GEMM1: h[r][tid] = tanh(b1 + sum_k xc[r][k]*W1[k][tid]) ----
        float a0 = bj, a1 = bj, a2 = bj, a3 = bj;
        #pragma unroll
        for (int k = 0; k < KD_; ++k) {
            const float4 xv = *(const float4*)&xcT[k][0];  // broadcast read
            const float  w  = w1[k];
            a0 += xv.x * w;
            a1 += xv.y * w;
            a2 += xv.z * w;
            a3 += xv.w * w;
        }
        hbuf[0][tid] = tanhf(a0);
        hbuf[1][tid] = tanhf(a1);
        hbuf[2][tid] = tanhf(a2);
        hbuf[3][tid] = tanhf(a3);
        __syncthreads();   // barrier1: hbuf visible; GEMM1's xcT reads done

        // write prefetched ctrl (step t's GEMM1 reads are done)
        if (loader && (t + 1 < T_)) xcT[SD_ + lc][lr] = cpre;

        // ---- GEMM2 partials: wave jc covers j in [jc*64, jc*64+64) ----
        float p0 = 0.f, p1 = 0.f, p2 = 0.f, p3 = 0.f;
        #pragma unroll
        for (int j4 = 0; j4 < 64; j4 += 4) {
            const float4 h0 = *(const float4*)&hbuf[0][jc * 64 + j4];  // broadcast
            const float4 h1 = *(const float4*)&hbuf[1][jc * 64 + j4];
            const float4 h2 = *(const float4*)&hbuf[2][jc * 64 + j4];
            const float4 h3 = *(const float4*)&hbuf[3][jc * 64 + j4];
            p0 += h0.x * w2[j4] + h0.y * w2[j4 + 1] + h0.z * w2[j4 + 2] + h0.w * w2[j4 + 3];
            p1 += h1.x * w2[j4] + h1.y * w2[j4 + 1] + h1.z * w2[j4 + 2] + h1.w * w2[j4 + 3];
            p2 += h2.x * w2[j4] + h2.y * w2[j4 + 1] + h2.z * w2[j4 + 2] + h2.w * w2[j4 + 3];
            p3 += h3.x * w2[j4] + h3.y * w2[j4 + 1] + h3.z * w2[j4 + 2] + h3.w * w2[j4 + 3];
        }
        part[0][sl][jc] = p0;
        part[1][sl][jc] = p1;
        part[2][sl][jc] = p2;
        part[3][sl][jc] = p3;
        __syncthreads();   // barrier2: partials visible

        // ---- final reduce + state update: tid < 256, one (r,s) each ----
        if (tid < ROWS_ * SD_) {
            const float* __restrict__ pp = &part[rf][sf][0];
            float acc = pp[0];
            acc += pp[1]; acc += pp[2]; acc += pp[3];
            acc += pp[4]; acc += pp[5]; acc += pp[6]; acc += pp[7];
            const float xnew = xcT[sf][rf] + DT_ * (acc + bs);
            xcT[sf][rf] = xnew;
            out[(size_t)(r0 + rf) * (T_ + 1) * SD_ + (size_t)(t + 1) * SD_ + sf] = xnew;
        }
        __syncthreads();   // barrier3: new state + ctrl visible for next GEMM1
    }
}

extern "C" void kernel_launch(void* const* d_in, const int* in_sizes, int n_in,
                              void* d_out, int out_size, void* d_ws, size_t ws_size,
                              hipStream_t stream) {
    const float* x0   = (const float*)d_in[0];
    const float* ctrl = (const float*)d_in[1];
    const float* W1   = (const float*)d_in[2];
    const float* b1   = (const float*)d_in[3];
    const float* W2   = (const float*)d_in[4];
    const float* b2   = (const float*)d_in[5];
    float* out = (float*)d_out;

    dim3 grid(B_ / ROWS_);      // 256 blocks -> 1 per CU (persistent)
    dim3 block(THREADS_);
    rollout_regw_kernel<<<grid, block, 0, stream>>>(x0, ctrl, W1, b1, W2, b2, out);
}

// Round 4
// 14870.152 us; speedup vs baseline: 1.1760x; 1.1760x over previous
//
#include <hip/hip_runtime.h>
#include <cstddef>

// DifferentiableRollout: x_{t+1} = x + DT * ( tanh([x,u]@W1 + b1) @ W2 + b2 )
// B=1024, T=200, SD=64, CD=32, H=512.  fp32 only (R0 measured: fp32 reorder
// noise alone -> absmax 0.25 of 1.245 threshold; bf16's 4e-3 rel error would
// amplify ~1e4x past threshold through the 200-step chaotic rollout).
//
// R4 = R1's register-resident-weights design + the spill fix.
//   R3 post-mortem: compiler targeted 4 waves/EU (VGPR_Count=128) despite
//   __launch_bounds__(512,2), spilling w1[96]+w2[64] -> 33 GB FETCH of
//   scratch thrash, 17.5 ms.  Fix: amdgpu_waves_per_eu(2,2) pins min=max=2
//   waves/EU -> 256-VGPR budget -> ~190-reg demand fits, zero spill.
//  - 256 blocks x 512 threads, 4 rows/block, persistent across all 200 steps.
//  - Thread tid owns W1 column tid (96 VGPRs).  GEMM1: x broadcast from LDS
//    (wave-uniform b128 = conflict-free), 4 independent FMA chains.
//  - Wave jc owns W2 rows [jc*64,(jc+1)*64); lane sl holds W2[j][sl] (64
//    VGPRs).  GEMM2: rank-64 partials, h broadcast from LDS, then 8-chunk
//    reduce.  part layout [r][jc][s]: writes AND reads lane-consecutive
//    (R1 had [r][s][jc] -> 16-way write conflicts).
//  - Controls prefetched one step ahead.  3 barriers/step.

constexpr int B_  = 1024;
constexpr int T_  = 200;
constexpr int SD_ = 64;
constexpr int CD_ = 32;
constexpr int H_  = 512;
constexpr int KD_ = SD_ + CD_;   // 96
constexpr float DT_ = 0.1f;
constexpr int ROWS_ = 4;
constexpr int THREADS_ = 512;

__global__ __launch_bounds__(THREADS_)
__attribute__((amdgpu_waves_per_eu(2, 2)))
void rollout_regw_kernel(
    const float* __restrict__ x0,     // [B, SD]
    const float* __restrict__ ctrl,   // [B, T, CD]
    const float* __restrict__ W1,     // [KD, H]
    const float* __restrict__ b1,     // [H]
    const float* __restrict__ W2,     // [H, SD]
    const float* __restrict__ b2,     // [SD]
    float* __restrict__ out)          // [B, T+1, SD]
{
    __shared__ float xcT[KD_][ROWS_];       // state+control, transposed (16B rows)
    __shared__ float hbuf[ROWS_][H_];       // activations
    __shared__ float part[ROWS_][8][SD_];   // GEMM2 partials [r][jc][s]

    const int tid = threadIdx.x;
    const int r0  = blockIdx.x * ROWS_;

    // ---- hoist weights into registers (once per 200 steps) ----
    float w1[KD_];
    #pragma unroll
    for (int k = 0; k < KD_; ++k)
        w1[k] = W1[(size_t)k * H_ + tid];          // coalesced: lanes j=tid

    const int jc = tid >> 6;                        // wave id 0..7 = W2 chunk
    const int sl = tid & 63;                        // lane 0..63 = output col s
    float w2[64];
    #pragma unroll
    for (int j = 0; j < 64; ++j)
        w2[j] = W2[(size_t)(jc * 64 + j) * SD_ + sl];  // coalesced per lane

    const float bj = b1[tid];

    // final-update mapping (tid < 256): (rf, sf)
    const int rf = (tid >> 6) & 3;
    const int sf = tid & 63;
    const float bs = b2[sf];

    // ctrl loader mapping: tid in [256, 384)
    const int  lt = tid - 256;
    const bool loader = (lt >= 0) && (lt < ROWS_ * CD_);
    const int  lr = (lt >> 5) & 3;
    const int  lc = lt & 31;
    const size_t ctrl_base = (size_t)(r0 + lr) * T_ * CD_ + lc;

    // ---- init: x0 into xcT + states[:,0,:], ctrl[0] into xcT ----
    if (tid < ROWS_ * SD_) {
        const float v = x0[(size_t)(r0 + rf) * SD_ + sf];
        xcT[sf][rf] = v;
        out[(size_t)(r0 + rf) * (T_ + 1) * SD_ + sf] = v;
    }
    if (loader) xcT[SD_ + lc][lr] = ctrl[ctrl_base];
    __syncthreads();

    for (int t = 0; t < T_; ++t) {
        // ---- prefetch next step's controls (consumed after barrier1) ----
        float cpre = 0.f;
        if (loader && (t + 1 < T_))
            cpre = ctrl[ctrl_base + (size_t)(t + 1) * CD_];

        // ---- GEMM1: h[r][tid] = tanh(b1 + sum_k xc[r][k]*W1[k][tid]) ----
        float a0 = bj, a1 = bj, a2 = bj, a3 = bj;
        #pragma unroll
        for (int k = 0; k < KD_; ++k) {
            const float4 xv = *(const float4*)&xcT[k][0];  // broadcast read
            const float  w  = w1[k];
            a0 += xv.x * w;
            a1 += xv.y * w;
            a2 += xv.z * w;
            a3 += xv.w * w;
        }
        hbuf[0][tid] = tanhf(a0);
        hbuf[1][tid] = tanhf(a1);
        hbuf[2][tid] = tanhf(a2);
        hbuf[3][tid] = tanhf(a3);
        __syncthreads();   // barrier1: hbuf visible; GEMM1's xcT reads done

        // write prefetched ctrl (step t's GEMM1 reads are done)
        if (loader && (t + 1 < T_)) xcT[SD_ + lc][lr] = cpre;

        // ---- GEMM2 partials: wave jc covers j in [jc*64, jc*64+64) ----
        // per-row inner loops keep live float4 count low (reg pressure).
        {
            const int jb = jc * 64;
            #pragma unroll
            for (int r = 0; r < ROWS_; ++r) {
                float p = 0.f;
                #pragma unroll
                for (int j4 = 0; j4 < 64; j4 += 4) {
                    const float4 hv = *(const float4*)&hbuf[r][jb + j4];  // broadcast
                    p += hv.x * w2[j4]     + hv.y * w2[j4 + 1]
                       + hv.z * w2[j4 + 2] + hv.w * w2[j4 + 3];
                }
                part[r][jc][sl] = p;       // lane-consecutive: conflict-free
            }
        }
        __syncthreads();   // barrier2: partials visible

        // ---- final reduce + state update: tid < 256, one (r,s) each ----
        if (tid < ROWS_ * SD_) {
            float acc = part[rf][0][sf];
            #pragma unroll
            for (int c = 1; c < 8; ++c) acc += part[rf][c][sf];  // lane-consecutive
            const float xnew = xcT[sf][rf] + DT_ * (acc + bs);
            xcT[sf][rf] = xnew;
            out[(size_t)(r0 + rf) * (T_ + 1) * SD_ + (size_t)(t + 1) * SD_ + sf] = xnew;
        }
        __syncthreads();   // barrier3: new state + ctrl visible for next GEMM1
    }
}

extern "C" void kernel_launch(void* const* d_in, const int* in_sizes, int n_in,
                              void* d_out, int out_size, void* d_ws, size_t ws_size,
                              hipStream_t stream) {
    const float* x0   = (const float*)d_in[0];
    const float* ctrl = (const float*)d_in[1];
    const float* W1   = (const float*)d_in[2];
    const float* b1   = (const float*)d_in[3];
    const float* W2   = (const float*)d_in[4];
    const float* b2   = (const float*)d_in[5];
    float* out = (float*)d_out;

    dim3 grid(B_ / ROWS_);      // 256 blocks -> 1 per CU (persistent)
    dim3 block(THREADS_);
    rollout_regw_kernel<<<grid, block, 0, stream>>>(x0, ctrl, W1, b1, W2, b2, out);
}

// Round 5
// 788.612 us; speedup vs baseline: 22.1744x; 18.8561x over previous
//
#include <hip/hip_runtime.h>
#include <cstddef>

// DifferentiableRollout: x_{t+1} = x + DT * ( tanh([x,u]@W1 + b1) @ W2 + b2 )
// B=1024, T=200, SD=64, CD=32, H=512.  fp32 only (R0: fp32 reorder noise
// alone -> absmax 0.25 of 1.245 threshold; bf16 would amplify past it).
//
// R5: fit the weights in the 128-VGPR envelope the allocator actually grants.
//   R3/R4 post-mortem: both __launch_bounds__(512,2) and
//   amdgpu_waves_per_eu(2,2) failed to raise VGPR_Count past 128; the
//   160-float weight arrays spilled to scratch -> 33 GB/17.6 GB HBM thrash.
//   Fix: 1024 threads/block, half the weights per thread:
//  - GEMM1: thread (g=tid>>9, j=tid&511) owns W1[k in 48g..48g+48)][j]
//    (48 regs).  g=1 writes rank-48 partials to LDS; g=0 adds its half,
//    + b1, tanh -> hbuf.  x read as wave-uniform float4 broadcast (free).
//  - GEMM2: wave wv (0..15) owns W2 rows [32wv,32wv+32); lane sl holds
//    W2[.][sl] (32 regs).  Rank-32 partials -> part2[r][wv][sl]
//    (lane-consecutive, conflict-free), 16-chunk reduce by tid<256.
//  - Per-thread weight regs: 48+32=80; total demand ~110 < 128 -> no spill.
//  - 256 blocks -> 1 block/CU, 16 waves/CU.  4 barriers/step.
//  - Controls prefetched one step ahead by otherwise-idle g=1 threads.

constexpr int B_  = 1024;
constexpr int T_  = 200;
constexpr int SD_ = 64;
constexpr int CD_ = 32;
constexpr int H_  = 512;
constexpr int KD_ = SD_ + CD_;   // 96
constexpr float DT_ = 0.1f;
constexpr int ROWS_ = 4;
constexpr int THREADS_ = 1024;
constexpr int KHALF_ = 48;       // K split per g
constexpr int CHUNK_ = 32;       // W2 rows per wave (H / 16 waves)

__global__ __launch_bounds__(THREADS_)
void rollout_split_kernel(
    const float* __restrict__ x0,     // [B, SD]
    const float* __restrict__ ctrl,   // [B, T, CD]
    const float* __restrict__ W1,     // [KD, H]
    const float* __restrict__ b1,     // [H]
    const float* __restrict__ W2,     // [H, SD]
    const float* __restrict__ b2,     // [SD]
    float* __restrict__ out)          // [B, T+1, SD]
{
    __shared__ float xcT[KD_][ROWS_];        // state+control, transposed (16B rows)
    __shared__ float part1[ROWS_][H_];       // GEMM1 rank-48 partials (g=1)
    __shared__ float hbuf[ROWS_][H_];        // activations
    __shared__ float part2[ROWS_][16][SD_];  // GEMM2 partials [r][wv][s]

    const int tid = threadIdx.x;
    const int r0  = blockIdx.x * ROWS_;

    // ---- GEMM1 mapping: half-column of W1 in registers ----
    const int j     = tid & (H_ - 1);   // 0..511
    const int g     = tid >> 9;         // 0 or 1 (wave-uniform)
    const int kbase = g * KHALF_;
    float w1p[KHALF_];
    #pragma unroll
    for (int i = 0; i < KHALF_; ++i)
        w1p[i] = W1[(size_t)(kbase + i) * H_ + j];       // coalesced

    // ---- GEMM2 mapping: 32-row W2 chunk per wave ----
    const int wv = tid >> 6;            // 0..15 (wave id)
    const int sl = tid & 63;
    const int jb = wv * CHUNK_;
    float w2p[CHUNK_];
    #pragma unroll
    for (int i = 0; i < CHUNK_; ++i)
        w2p[i] = W2[(size_t)(jb + i) * SD_ + sl];        // coalesced

    const float bj = b1[j];             // used by g==0 finishers

    // reduce/update mapping (tid < 256)
    const int rf = (tid >> 6) & 3;
    const int sf = tid & 63;
    const float bs = b2[sf];

    // ctrl loader: tids [512, 640) -- g==1 threads, idle during tanh phase
    const int  lt = tid - 512;
    const bool loader = (lt >= 0) && (lt < ROWS_ * CD_);
    const int  lr = (lt >> 5) & 3;
    const int  lc = lt & 31;
    const size_t ctrl_base = (size_t)(r0 + lr) * T_ * CD_ + lc;

    // ---- init: x0 into xcT + states[:,0,:], ctrl[0] into xcT ----
    if (tid < ROWS_ * SD_) {
        const float v = x0[(size_t)(r0 + rf) * SD_ + sf];
        xcT[sf][rf] = v;
        out[(size_t)(r0 + rf) * (T_ + 1) * SD_ + sf] = v;
    }
    if (loader) xcT[SD_ + lc][lr] = ctrl[ctrl_base];
    __syncthreads();

    for (int t = 0; t < T_; ++t) {
        // ---- prefetch next step's controls into a register ----
        float cpre = 0.f;
        if (loader && (t + 1 < T_))
            cpre = ctrl[ctrl_base + (size_t)(t + 1) * CD_];

        // ---- GEMM1 rank-48 partials: 4 rows per thread ----
        float a0 = 0.f, a1 = 0.f, a2 = 0.f, a3 = 0.f;
        #pragma unroll
        for (int i = 0; i < KHALF_; ++i) {
            const float4 xv = *(const float4*)&xcT[kbase + i][0];  // broadcast
            const float  w  = w1p[i];
            a0 += xv.x * w;
            a1 += xv.y * w;
            a2 += xv.z * w;
            a3 += xv.w * w;
        }
        if (g == 1) {
            part1[0][j] = a0;  part1[1][j] = a1;   // lane-consecutive
            part1[2][j] = a2;  part1[3][j] = a3;
        }
        __syncthreads();   // A: part1 visible; all xcT reads for step t done

        if (g == 0) {
            hbuf[0][j] = tanhf(bj + a0 + part1[0][j]);
            hbuf[1][j] = tanhf(bj + a1 + part1[1][j]);
            hbuf[2][j] = tanhf(bj + a2 + part1[2][j]);
            hbuf[3][j] = tanhf(bj + a3 + part1[3][j]);
        } else if (loader && (t + 1 < T_)) {
            xcT[SD_ + lc][lr] = cpre;   // safe: step-t xcT reads done at A
        }
        __syncthreads();   // B: hbuf visible

        // ---- GEMM2 rank-32 partials: wave wv covers j in [jb, jb+32) ----
        #pragma unroll
        for (int r = 0; r < ROWS_; ++r) {
            float p = 0.f;
            #pragma unroll
            for (int i4 = 0; i4 < CHUNK_; i4 += 4) {
                const float4 hv = *(const float4*)&hbuf[r][jb + i4];  // broadcast
                p += hv.x * w2p[i4]     + hv.y * w2p[i4 + 1]
                   + hv.z * w2p[i4 + 2] + hv.w * w2p[i4 + 3];
            }
            part2[r][wv][sl] = p;       // lane-consecutive: conflict-free
        }
        __syncthreads();   // C: part2 visible

        // ---- 16-chunk reduce + state update: tid < 256 ----
        if (tid < ROWS_ * SD_) {
            float acc = part2[rf][0][sf];
            #pragma unroll
            for (int c = 1; c < 16; ++c) acc += part2[rf][c][sf];
            const float xnew = xcT[sf][rf] + DT_ * (acc + bs);
            xcT[sf][rf] = xnew;
            out[(size_t)(r0 + rf) * (T_ + 1) * SD_ + (size_t)(t + 1) * SD_ + sf] = xnew;
        }
        __syncthreads();   // D: new state visible; part2 reads done
    }
}

extern "C" void kernel_launch(void* const* d_in, const int* in_sizes, int n_in,
                              void* d_out, int out_size, void* d_ws, size_t ws_size,
                              hipStream_t stream) {
    const float* x0   = (const float*)d_in[0];
    const float* ctrl = (const float*)d_in[1];
    const float* W1   = (const float*)d_in[2];
    const float* b1   = (const float*)d_in[3];
    const float* W2   = (const float*)d_in[4];
    const float* b2   = (const float*)d_in[5];
    float* out = (float*)d_out;

    dim3 grid(B_ / ROWS_);      // 256 blocks -> 1 per CU (persistent)
    dim3 block(THREADS_);
    rollout_split_kernel<<<grid, block, 0, stream>>>(x0, ctrl, W1, b1, W2, b2, out);
}